// Round 1
// 310.084 us; speedup vs baseline: 1.0592x; 1.0592x over previous
//
#include <hip/hip_runtime.h>
#include <hip/hip_bf16.h>

// Problem constants
#define NB     8
#define NPTS   4096
#define DIMC   64
#define KNN_K  8
#define NBLK   12
#define NREP   8      // stats replicas (atomic de-contention)

// ---------------------------------------------------------------------------
// Kernel 0: zero the stats buffers (13 stages x 8 replicas x 128 floats).
// ws is poisoned with 0xAA before every timed launch — re-zero every call.
// ---------------------------------------------------------------------------
__global__ void zero_stats_kernel(float* __restrict__ stats) {
    int i = threadIdx.x + blockIdx.x * 256;
    if (i < 13 * NREP * 128) stats[i] = 0.0f;
}

// ---------------------------------------------------------------------------
// Kernel 0b: precompute (x, y, z, |x|^2) per point for the KNN kernel.
// sq formula matches numpy bit-for-bit (contract off, sequential adds).
// ---------------------------------------------------------------------------
__global__ __launch_bounds__(256) void prep_kernel(
        const float* __restrict__ xyz, float4* __restrict__ pts4g) {
#pragma clang fp contract(off)
    int g = blockIdx.x * 256 + threadIdx.x;      // 0..32767
    int b = g >> 12, j = g & 4095;
    const float* xb = xyz + (size_t)b * 3 * NPTS;
    float x = xb[j];
    float y = xb[NPTS + j];
    float z = xb[2 * NPTS + j];
    float sq = (x * x + y * y) + z * z;
    pts4g[g] = make_float4(x, y, z, sq);
}

// ---------------------------------------------------------------------------
// Kernel 1: transpose fp32 points [b][d][n] -> point-major P0[b][n][d],
// fused with stats[0] accumulation. XCD-affine: b = blockIdx & 7 so batch
// b's P-slice is written from XCD b's CUs and stays in its L2 for the
// block kernels (blockIdx%8 -> XCD round-robin heuristic).
// Grid: 512 WGs, 256 threads.
// ---------------------------------------------------------------------------
__global__ __launch_bounds__(256) void cast_kernel(
        const float* __restrict__ pts,
        float* __restrict__ P0, float* __restrict__ stats0) {
    __shared__ __align__(16) float tr[64 * 65];      // [d][n] transpose tile (+1 pad)
    __shared__ float slotA[4 * 64], slotB[4 * 64];
    int wg = blockIdx.x;
    int b = wg & 7;                  // XCD affinity
    int n0 = (wg >> 3) << 6;
    int rep = (wg >> 3) & (NREP - 1);
    int tid = threadIdx.x;
    int lane6 = tid & 63;
    int grp = tid >> 6;              // 0..3

    #pragma unroll
    for (int k = 0; k < 16; ++k) {
        int d = grp + (k << 2);
        float v = pts[(((size_t)((b << 6) + d)) << 12) + n0 + lane6];
        tr[d * 65 + lane6] = v;
    }
    __syncthreads();
    int c = lane6;
    float s = 0.0f, s2 = 0.0f;
    #pragma unroll
    for (int k = 0; k < 16; ++k) {
        int p = grp + (k << 2);
        float v = tr[c * 65 + p];
        P0[((size_t)((b << 12) + n0 + p)) * 64 + c] = v;
        s += v; s2 += v * v;
    }
    slotA[grp * 64 + c] = s;
    slotB[grp * 64 + c] = s2;
    __syncthreads();
    if (tid < 64) {
        float t = slotA[tid] + slotA[64 + tid] + slotA[128 + tid] + slotA[192 + tid];
        atomicAdd(&stats0[rep * 128 + tid], t);
    } else if (tid < 128) {
        int cc = tid - 64;
        float t = slotB[cc] + slotB[64 + cc] + slotB[128 + cc] + slotB[192 + cc];
        atomicAdd(&stats0[rep * 128 + 64 + cc], t);
    }
}

// ---------------------------------------------------------------------------
// Kernel 2: brute-force 8-NN, one query per lane, f64-key top-8.
// Candidates staged in 2048-point HALVES (32 KB vs 64 KB) so LDS = 68 KB
// -> 2 WGs/CU. Chunk c scans [512c, 512c+512) of each half.
// key = f64(d2) | idx (12 low mantissa bits; order-preserving; keys are
// UNIQUE, so the top-8 SET is insertion-order independent).
//
// Insert scheme (this revision): the old per-candidate `if (d2 < bd7f)
// insert` executed the 16-op f64 chain at the WAVE-UNION hit rate
// (~730/1024 iterations: all 64 lanes share candidate j, any lane's hit
// drags the whole wave through the chain). Now:
//   - first 128 candidates (union rate ~100%): unconditional insert,
//     zero branches;
//   - remaining: per 8-candidate group build a per-lane hitmask
//     branchlessly, then drain with while(__any(hm)): each pending lane
//     pops ITS OWN lowest-set bit (cndmask-tree d2 select). Chain
//     executions drop to per-group max-over-lanes (~350), branches to
//     ~1 ballot/group. Chain is a no-op for keys >= k7, so stale-
//     threshold false positives are harmless; unique keys make drain
//     order irrelevant. d2 formula unchanged (bit-exact, contract off).
// Stash layout [(c*9+t)*128+q]: lanes -> consecutive doubles.
// Grid: 8 b x 32 q-tiles of 128 = 256 WGs, 512 threads.
// ---------------------------------------------------------------------------
__global__ __launch_bounds__(512) void knn_kernel(
        const float4* __restrict__ pts4g, int* __restrict__ idx) {
#pragma clang fp contract(off)
    __shared__ __align__(16) float4 cand[2048];      // 32 KB
    __shared__ double stash[4 * 9 * 128];            // 36 KB
    int wg = blockIdx.x;
    int b = wg >> 5;
    int q0 = (wg & 31) << 7;
    int tid = threadIdx.x;                           // 0..511

    int lane  = tid & 63;
    int wave  = tid >> 6;            // 0..7
    int chunk = wave & 3;
    int qgrp  = wave >> 2;           // 0..1
    int q_l   = (qgrp << 6) | lane;  // 0..127

    const float4* cb = pts4g + ((size_t)b << 12);
    float4 qp = cb[q0 + q_l];

    double k0, k1, k2, k3, k4, k5, k6, k7;
    k0 = k1 = k2 = k3 = k4 = k5 = k6 = k7 = __builtin_inf();
    float bd7f = 3.4e38f;

    for (int half = 0; half < 2; ++half) {
        if (half) __syncthreads();                   // drain readers before restage
        #pragma unroll
        for (int k = 0; k < 4; ++k)
            cand[tid + (k << 9)] = cb[(half << 11) + tid + (k << 9)];
        __syncthreads();

        int jl0 = chunk << 9;                        // local staged offset
        int jg0 = (half << 11) | (chunk << 9);       // global candidate index
        int jstart = 0;

        if (half == 0) {
            // --- direct phase: first 128 candidates, unconditional ---
            for (int jo = 0; jo < 128; jo += 8) {
                float d2v[8];
                #pragma unroll
                for (int u = 0; u < 8; ++u) {
                    float4 p = cand[jl0 + jo + u];
                    float dot = (qp.x * p.x + qp.y * p.y) + qp.z * p.z;
                    d2v[u] = (qp.w - 2.0f * dot) + p.w;
                }
                #pragma unroll
                for (int u = 0; u < 8; ++u) {
                    unsigned long long kb =
                        __double_as_longlong((double)d2v[u]) |
                        (unsigned long long)(jg0 + jo + u);
                    double key = __longlong_as_double(kb);
                    double n0 = fmin(k0, key);
                    double n1 = fmin(k1, fmax(k0, key));
                    double n2 = fmin(k2, fmax(k1, key));
                    double n3 = fmin(k3, fmax(k2, key));
                    double n4 = fmin(k4, fmax(k3, key));
                    double n5 = fmin(k5, fmax(k4, key));
                    double n6 = fmin(k6, fmax(k5, key));
                    double n7 = fmin(k7, fmax(k6, key));
                    k0 = n0; k1 = n1; k2 = n2; k3 = n3;
                    k4 = n4; k5 = n5; k6 = n6; k7 = n7;
                }
            }
            bd7f = (float)k7;
            jstart = 128;
        }

        // --- queued phase: branchless hitmask + wave drain ---
        for (int jo = jstart; jo < 512; jo += 8) {
            float d2v[8];
            unsigned hm = 0u;
            #pragma unroll
            for (int u = 0; u < 8; ++u) {
                float4 p = cand[jl0 + jo + u];
                float dot = (qp.x * p.x + qp.y * p.y) + qp.z * p.z;
                float d2 = (qp.w - 2.0f * dot) + p.w;
                d2v[u] = d2;
                hm |= (d2 < bd7f) ? (1u << u) : 0u;
            }
            while (__any(hm != 0u)) {
                if (hm) {
                    int u = __builtin_ctz(hm);
                    hm &= hm - 1u;
                    // cndmask tree: d2 = d2v[u] with static indexing only
                    float t0 = (u & 1) ? d2v[1] : d2v[0];
                    float t1 = (u & 1) ? d2v[3] : d2v[2];
                    float t2 = (u & 1) ? d2v[5] : d2v[4];
                    float t3 = (u & 1) ? d2v[7] : d2v[6];
                    float s0 = (u & 2) ? t1 : t0;
                    float s1 = (u & 2) ? t3 : t2;
                    float d2 = (u & 4) ? s1 : s0;
                    unsigned long long kb =
                        __double_as_longlong((double)d2) |
                        (unsigned long long)(jg0 + jo + u);
                    double key = __longlong_as_double(kb);
                    double n0 = fmin(k0, key);
                    double n1 = fmin(k1, fmax(k0, key));
                    double n2 = fmin(k2, fmax(k1, key));
                    double n3 = fmin(k3, fmax(k2, key));
                    double n4 = fmin(k4, fmax(k3, key));
                    double n5 = fmin(k5, fmax(k4, key));
                    double n6 = fmin(k6, fmax(k5, key));
                    double n7 = fmin(k7, fmax(k6, key));
                    k0 = n0; k1 = n1; k2 = n2; k3 = n3;
                    k4 = n4; k5 = n5; k6 = n6; k7 = n7;
                }
            }
            bd7f = (float)k7;
        }
    }

    {
        double* S = &stash[(chunk * 9) * 128 + q_l];
        S[0 * 128] = k0; S[1 * 128] = k1; S[2 * 128] = k2; S[3 * 128] = k3;
        S[4 * 128] = k4; S[5 * 128] = k5; S[6 * 128] = k6; S[7 * 128] = k7;
        S[8 * 128] = __builtin_inf();    // merge guard
    }
    __syncthreads();

    // 4-way merge per query by key (threads 0..127)
    if (tid < 128) {
        int h0 = 0, h1 = 0, h2 = 0, h3 = 0;
        int* op = idx + ((size_t)(b * NPTS + q0 + tid)) * 8;
        #pragma unroll
        for (int t = 0; t < 8; ++t) {
            double b0 = stash[(0 * 9 + h0) * 128 + tid];
            double b1 = stash[(1 * 9 + h1) * 128 + tid];
            double b2 = stash[(2 * 9 + h2) * 128 + tid];
            double b3 = stash[(3 * 9 + h3) * 128 + tid];
            double best = b0; int bc = 0;
            if (b1 < best) { best = b1; bc = 1; }
            if (b2 < best) { best = b2; bc = 2; }
            if (b3 < best) { best = b3; bc = 3; }
            h0 += (bc == 0); h1 += (bc == 1);
            h2 += (bc == 2); h3 += (bc == 3);
            op[t] = (int)(__double_as_longlong(best) & 0xFFFULL);
        }
    }
}

// ---------------------------------------------------------------------------
// Kernel 3 (x12): one residual block, fully fused. XCD-affine b = wg & 7:
// batch b's P slices live in XCD b's L2 (written there by cast/previous
// block) -> the 8-neighbor gather hits local L2 instead of LLC.
//   - self rows staged once in LDS (serves h_self AND the residual;
//     cuts 36 -> 32 global loads/thread and 16 MB/kernel of re-reads)
//   - BN affine from 8-replica stats (summed here)
//   - GEMM 64x64 per point, fp32 VALU, 4x4 register tile
//   - stats for NEXT block -> replica (wg>>3)&7 (64-way contention, not 512)
//   - last block: fp32 output in [b][d][n] via LDS transpose
// Grid: 512 WGs (64 tiles x 8 b), 256 threads. LDS ~54 KB -> 2 WG/CU.
// ---------------------------------------------------------------------------
__global__ __launch_bounds__(256) void block_kernel(
        const float* __restrict__ Pin, float* __restrict__ Pout,
        const float* __restrict__ statsIn, float* __restrict__ statsOut,
        const float* __restrict__ Wp, const float* __restrict__ Bp,
        const float* __restrict__ Gp, const float* __restrict__ Betap,
        const int* __restrict__ gidx, float* __restrict__ dout, int last) {
    __shared__ __align__(16) float Wt[64 * 68];      // W transposed: Wt[d][o]
    __shared__ __align__(16) float mt[64 * 68];      // m[d][pt]
    __shared__ __align__(16) float selft[64 * 64];   // raw self rows [pt][c]
    __shared__ __align__(16) int   idxl[64 * 8];
    __shared__ __align__(16) float scale_l[64], shift_l[64], bias_l[64];
    __shared__ float slot[4 * 128];

    int wg = blockIdx.x;
    int b = wg & 7;                  // XCD affinity
    int n0 = (wg >> 3) << 6;
    int rep = (wg >> 3) & (NREP - 1);
    int tid = threadIdx.x;

    const float* Pb = Pin + (((size_t)b) << 18);     // batch slice [4096][64]

    // --- setup: idx tile, self tile, W^T, BN affine (replica-summed) ---
    if (tid < 128) {
        ((int4*)idxl)[tid] = ((const int4*)(gidx + ((size_t)(b * NPTS + n0)) * 8))[tid];
    }
    #pragma unroll
    for (int k = 0; k < 4; ++k) {    // self rows: 64 pts x 64 ch, coalesced
        int lin = tid + (k << 8);    // float4 id
        ((float4*)selft)[lin] = ((const float4*)&Pb[(size_t)n0 << 6])[lin];
    }
    #pragma unroll
    for (int k = 0; k < 16; ++k) {
        int lin = tid + (k << 8);
        int o = lin >> 6, d = lin & 63;
        Wt[d * 68 + o] = Wp[lin];
    }
    if (tid < 64) {
        int c = tid;
        float sum = 0.0f, sumsq = 0.0f;
        #pragma unroll
        for (int r = 0; r < NREP; ++r) {
            sum   += statsIn[r * 128 + c];
            sumsq += statsIn[r * 128 + 64 + c];
        }
        float mean = sum * (1.0f / 32768.0f);
        float var  = sumsq * (1.0f / 32768.0f) - mean * mean;
        float rs   = 1.0f / sqrtf(var + 1e-5f);
        float sc   = Gp[c] * rs;
        scale_l[c] = sc;
        shift_l[c] = Betap[c] - mean * sc;
        bias_l[c]  = Bp[c];
    }
    __syncthreads();

    // --- gather: m[d][pt]; self from LDS, 8 neighbors from (local-L2) global ---
    {
        int cq = tid & 15;           // channel quad: channels 4cq..4cq+3
        int pg = tid >> 4;           // 0..15: points 4pg..4pg+3
        int c4 = cq << 2;
        float4 sc4 = *(const float4*)&scale_l[c4];
        float4 sh4 = *(const float4*)&shift_l[c4];
        #pragma unroll
        for (int i = 0; i < 4; ++i) {
            int pt = (pg << 2) + i;
            int4 ja = *(const int4*)&idxl[pt * 8];
            int4 jb = *(const int4*)&idxl[pt * 8 + 4];
            float4 v[9];
            v[0] = *(const float4*)&selft[(pt << 6) + c4];
            v[1] = *(const float4*)&Pb[(((size_t)ja.x) << 6) + c4];
            v[2] = *(const float4*)&Pb[(((size_t)ja.y) << 6) + c4];
            v[3] = *(const float4*)&Pb[(((size_t)ja.z) << 6) + c4];
            v[4] = *(const float4*)&Pb[(((size_t)ja.w) << 6) + c4];
            v[5] = *(const float4*)&Pb[(((size_t)jb.x) << 6) + c4];
            v[6] = *(const float4*)&Pb[(((size_t)jb.y) << 6) + c4];
            v[7] = *(const float4*)&Pb[(((size_t)jb.z) << 6) + c4];
            v[8] = *(const float4*)&Pb[(((size_t)jb.w) << 6) + c4];
            float4 a = make_float4(0.f, 0.f, 0.f, 0.f);
            #pragma unroll
            for (int k = 0; k < 9; ++k) {
                float hx = v[k].x * sc4.x + sh4.x;
                float hy = v[k].y * sc4.y + sh4.y;
                float hz = v[k].z * sc4.z + sh4.z;
                float hw = v[k].w * sc4.w + sh4.w;
                a.x += fmaxf(hx, 0.01f * hx);
                a.y += fmaxf(hy, 0.01f * hy);
                a.z += fmaxf(hz, 0.01f * hz);
                a.w += fmaxf(hw, 0.01f * hw);
            }
            mt[(c4 + 0) * 68 + pt] = a.x * (1.0f / 9.0f);
            mt[(c4 + 1) * 68 + pt] = a.y * (1.0f / 9.0f);
            mt[(c4 + 2) * 68 + pt] = a.z * (1.0f / 9.0f);
            mt[(c4 + 3) * 68 + pt] = a.w * (1.0f / 9.0f);
        }
    }
    __syncthreads();

    // --- GEMM: out[pt][o] = sum_d Wt[d][o] * m[d][pt] + bias[o] ---
    int o0 = (tid & 15) << 2;
    int p0 = (tid >> 4) << 2;
    float4 acc[4];
    {
        float4 bias4 = *(const float4*)&bias_l[o0];
        acc[0] = bias4; acc[1] = bias4; acc[2] = bias4; acc[3] = bias4;
    }
    #pragma unroll
    for (int d = 0; d < 64; ++d) {
        float4 wv = *(const float4*)&Wt[d * 68 + o0];
        float4 a  = *(const float4*)&mt[d * 68 + p0];
        acc[0].x += wv.x * a.x; acc[0].y += wv.y * a.x; acc[0].z += wv.z * a.x; acc[0].w += wv.w * a.x;
        acc[1].x += wv.x * a.y; acc[1].y += wv.y * a.y; acc[1].z += wv.z * a.y; acc[1].w += wv.w * a.y;
        acc[2].x += wv.x * a.z; acc[2].y += wv.y * a.z; acc[2].z += wv.z * a.z; acc[2].w += wv.w * a.z;
        acc[3].x += wv.x * a.w; acc[3].y += wv.y * a.w; acc[3].z += wv.z * a.w; acc[3].w += wv.w * a.w;
    }

    // --- residual add (self rows from LDS) ---
    #pragma unroll
    for (int j = 0; j < 4; ++j) {
        float4 r = *(const float4*)&selft[((p0 + j) << 6) + o0];
        acc[j].x += r.x; acc[j].y += r.y; acc[j].z += r.z; acc[j].w += r.w;
    }

    if (!last) {
        float* PbOut = Pout + ((((size_t)b) << 12) + n0) * 64;
        #pragma unroll
        for (int j = 0; j < 4; ++j)
            *(float4*)&PbOut[((size_t)(p0 + j)) * 64 + o0] = acc[j];

        float4 s, s2;
        s.x = acc[0].x + acc[1].x + acc[2].x + acc[3].x;
        s.y = acc[0].y + acc[1].y + acc[2].y + acc[3].y;
        s.z = acc[0].z + acc[1].z + acc[2].z + acc[3].z;
        s.w = acc[0].w + acc[1].w + acc[2].w + acc[3].w;
        s2.x = acc[0].x*acc[0].x + acc[1].x*acc[1].x + acc[2].x*acc[2].x + acc[3].x*acc[3].x;
        s2.y = acc[0].y*acc[0].y + acc[1].y*acc[1].y + acc[2].y*acc[2].y + acc[3].y*acc[3].y;
        s2.z = acc[0].z*acc[0].z + acc[1].z*acc[1].z + acc[2].z*acc[2].z + acc[3].z*acc[3].z;
        s2.w = acc[0].w*acc[0].w + acc[1].w*acc[1].w + acc[2].w*acc[2].w + acc[3].w*acc[3].w;
        #pragma unroll
        for (int m = 16; m <= 32; m <<= 1) {
            s.x += __shfl_xor(s.x, m, 64);  s.y += __shfl_xor(s.y, m, 64);
            s.z += __shfl_xor(s.z, m, 64);  s.w += __shfl_xor(s.w, m, 64);
            s2.x += __shfl_xor(s2.x, m, 64); s2.y += __shfl_xor(s2.y, m, 64);
            s2.z += __shfl_xor(s2.z, m, 64); s2.w += __shfl_xor(s2.w, m, 64);
        }
        if ((tid & 63) < 16) {
            int w = tid >> 6;
            slot[w * 128 + o0 + 0] = s.x;  slot[w * 128 + o0 + 1] = s.y;
            slot[w * 128 + o0 + 2] = s.z;  slot[w * 128 + o0 + 3] = s.w;
            slot[w * 128 + 64 + o0 + 0] = s2.x; slot[w * 128 + 64 + o0 + 1] = s2.y;
            slot[w * 128 + 64 + o0 + 2] = s2.z; slot[w * 128 + 64 + o0 + 3] = s2.w;
        }
        __syncthreads();
        if (tid < 128) {
            float t = slot[tid] + slot[128 + tid] + slot[256 + tid] + slot[384 + tid];
            atomicAdd(&statsOut[rep * 128 + tid], t);
        }
    } else {
        __syncthreads();                         // all mt reads done
        float* stage = mt;                       // reuse as [o][pt], 16 KB
        #pragma unroll
        for (int j = 0; j < 4; ++j) {
            stage[(o0 + 0) * 64 + p0 + j] = acc[j].x;
            stage[(o0 + 1) * 64 + p0 + j] = acc[j].y;
            stage[(o0 + 2) * 64 + p0 + j] = acc[j].z;
            stage[(o0 + 3) * 64 + p0 + j] = acc[j].w;
        }
        __syncthreads();
        #pragma unroll
        for (int k = 0; k < 16; ++k) {
            int lin = tid + (k << 8);
            int o = lin >> 6, pt = lin & 63;
            dout[(((size_t)((b << 6) + o)) << 12) + n0 + pt] = stage[lin];
        }
    }
}

// ---------------------------------------------------------------------------
extern "C" void kernel_launch(void* const* d_in, const int* in_sizes, int n_in,
                              void* d_out, int out_size, void* d_ws, size_t ws_size,
                              hipStream_t stream) {
    const float* xyz    = (const float*)d_in[0];
    const float* pts    = (const float*)d_in[1];
    const float* conv_w = (const float*)d_in[2];
    const float* conv_b = (const float*)d_in[3];
    const float* gamma  = (const float*)d_in[4];
    const float* beta   = (const float*)d_in[5];
    float* out = (float*)d_out;

    char* ws = (char*)d_ws;
    float*  P0    = (float*)(ws);                                  //  8 MB
    float*  P1    = (float*)(ws + (size_t)8 * 1024 * 1024);        //  8 MB
    int*    idx   = (int*)  (ws + (size_t)16 * 1024 * 1024);       //  1 MB
    float*  stats = (float*)(ws + (size_t)17 * 1024 * 1024);       // 52 KB
    float4* pts4g = (float4*)(ws + (size_t)18 * 1024 * 1024);      // 512 KB

    zero_stats_kernel<<<52, 256, 0, stream>>>(stats);
    prep_kernel<<<128, 256, 0, stream>>>(xyz, pts4g);
    cast_kernel<<<512, 256, 0, stream>>>(pts, P0, stats);
    knn_kernel<<<256, 512, 0, stream>>>(pts4g, idx);

    float* Pbuf[2] = {P0, P1};
    for (int t = 0; t < NBLK; ++t) {
        block_kernel<<<512, 256, 0, stream>>>(
            Pbuf[t & 1], Pbuf[(t + 1) & 1],
            stats + (size_t)t * NREP * 128, stats + (size_t)(t + 1) * NREP * 128,
            conv_w + (size_t)t * 4096, conv_b + (size_t)t * 64,
            gamma + (size_t)t * 64, beta + (size_t)t * 64,
            idx, out, (t == NBLK - 1) ? 1 : 0);
    }
}